// Round 13
// baseline (83.765 us; speedup 1.0000x reference)
//
#include <hip/hip_runtime.h>
#include <hip/hip_bf16.h>

// FMICLLoss: out = -mean(s_pos) + ALPHA * ( sum_{i!=j} exp(-d2_ij/2) / (N(N-1)) + EPS )
// N=8192, D=256, SIGMA=1 (inv2s2=0.5), ALPHA=1.5, EPS=1e-8, NORM_EPS=1e-12.
//
// Round 13: full-K B panels, ONE barrier per tile. A 128x256 fp8 panel is
// 32 KB, so LB dbuf = 64 KB = the 2-blocks/CU LDS budget, and A needs no
// resident LDS (read once per strip into VGPRs via the B buffers as scratch).
// vs R12: barriers/tile 2->1, prefetch window = full tile compute (~1900cyc)
// vs 32KB staging (~600-1100cyc) -> drains ~free; 32 uninterrupted MFMAs per
// tile. Staging swizzle = R6's verified 256B-stride mapping; reader = R5's
// verified full-K indexing; strip decode/epilogue = R12 (all absmax 0.0).
// Row-crossing (~12% of blocks) pays one exposed staging + readA (~1500cyc).
// ~48us of dur_us is harness ws re-poison fill + restores; ~17us is the 7
// dispatch boundaries per iteration (4 of them harness ops) — untouchable.

#define N_ROWS 8192
#define DIM    256
#define LOG2E  1.4426950408889634f
#define GRID   512

typedef __attribute__((ext_vector_type(8))) int   int8v;
typedef __attribute__((ext_vector_type(4))) float f32x4;

#define GLDS16(gptr, lptr) \
  __builtin_amdgcn_global_load_lds((const __attribute__((address_space(1))) void*)(gptr), \
                                   (__attribute__((address_space(3))) void*)(lptr), 16, 0, 0)

// ---------------------------------------------------------------------------
// Kernel 1: row-normalize z1 -> fp8, s_pos via Gram trick (one reduce phase).
// ---------------------------------------------------------------------------
__global__ __launch_bounds__(256) void norm_kernel(
    const float* __restrict__ z1, const float* __restrict__ z2,
    unsigned char* __restrict__ z1n8, float* __restrict__ spos_part) {

    int tid  = threadIdx.x;
    int wave = tid >> 6, lane = tid & 63;
    int row  = blockIdx.x * 4 + wave;

    const float4 a = *(const float4*)(z1 + (size_t)row * DIM + lane * 4);
    const float4 b = *(const float4*)(z2 + (size_t)row * DIM + lane * 4);

    float s1  = a.x*a.x + a.y*a.y + a.z*a.z + a.w*a.w;
    float s2  = b.x*b.x + b.y*b.y + b.z*b.z + b.w*b.w;
    float s12 = a.x*b.x + a.y*b.y + a.z*b.z + a.w*b.w;
    #pragma unroll
    for (int off = 32; off; off >>= 1) {       // 3 interleaved chains (ILP)
        s1  += __shfl_xor(s1,  off);
        s2  += __shfl_xor(s2,  off);
        s12 += __shfl_xor(s12, off);
    }
    float r1 = __builtin_amdgcn_rsqf(s1);
    float r2 = __builtin_amdgcn_rsqf(s2);

    int lo = __builtin_amdgcn_cvt_pk_fp8_f32(a.x * r1, a.y * r1, 0,  false);
    int pk = __builtin_amdgcn_cvt_pk_fp8_f32(a.z * r1, a.w * r1, lo, true);
    ((int*)(z1n8 + (size_t)row * DIM))[lane] = pk;

    __shared__ float sp[4];
    if (lane == 0) {
        float c = s12 * r1 * r2;               // d_pos = 2 - 2c
        sp[wave] = logf(__expf(c - 1.0f) + 1e-8f) + 1.0f;
    }
    __syncthreads();
    if (tid == 0)
        spos_part[blockIdx.x] = sp[0] + sp[1] + sp[2] + sp[3];
}

// ---------------------------------------------------------------------------
// Kernel 2: A-stationary fused fp8 Z·Z^T + exp-sum, upper block-triangle.
// Row-major strips (4-5 tiles sharing bi). Full-K 128x256 B panels, double-
// buffered (2 x 32 KB); A-frags strip-resident in VGPRs; 1 barrier per tile.
// ---------------------------------------------------------------------------
__global__ __launch_bounds__(256, 2) void pair_kernel(
    const unsigned char* __restrict__ z1n8, float* __restrict__ negp_part) {

    __shared__ unsigned char LB[2][128 * 256];   // 2 x 32 KB full-K panels
    __shared__ float red[4];

    const int tid = threadIdx.x, wave = tid >> 6, lane = tid & 63;
    const int bid = blockIdx.x;
    const int wr = wave >> 1, wc = wave & 1;
    const int quad = lane >> 4, colL = lane & 15;
    const int c7 = colL & 7;

    // strip [t0, t1) in row-major triangular order; cum(bi)=64bi-(bi-1)bi/2
    int t0, t1;
    if (bid < 480) { t0 = 4 * bid; t1 = t0 + 4; }
    else           { t0 = 1920 + 5 * (bid - 480); t1 = t0 + 5; }

    int bi = (int)((129.0f - sqrtf(16641.0f - 8.0f * (float)t0)) * 0.5f);
    if (bi < 0) bi = 0;
    while (64 * bi - (bi - 1) * bi / 2 > t0) --bi;
    while (64 * (bi + 1) - bi * (bi + 1) / 2 <= t0) ++bi;
    int bj = bi + (t0 - (64 * bi - (bi - 1) * bi / 2));

    // full-K staging (R6-verified): per issue 64 lanes x 16B = 4 rows x 256B;
    // row&7 = (q&1)*4 + rl -> two swizzled source pointers (q even/odd).
    // stored 16B-block cl holds logical block (cl & 8) | ((cl^row)&7).
    const int rl4 = lane >> 4, cl16 = lane & 15;
    const size_t offE = (size_t)(wave * 32 +     rl4) * DIM + ((cl16 ^  rl4     ) << 4);
    const size_t offO = (size_t)(wave * 32 + 4 + rl4) * DIM + ((cl16 ^ (rl4 + 4)) << 4);
    const int dstW = (wave * 32) * 256;

    auto stageFull = [&](int buf, int panel) {
        const unsigned char* g = z1n8 + (size_t)panel * (128 * DIM);
        unsigned char* d = &LB[buf][dstW];
        #pragma unroll
        for (int h = 0; h < 4; ++h) {
            GLDS16(g + offE + h * 2048, d + (2*h    ) * 1024);
            GLDS16(g + offO + h * 2048, d + (2*h + 1) * 1024);
        }
    };

    int8v af[2][4];                  // A-frags: 64 VGPRs, strip-resident
    auto readA = [&](int buf) {
        #pragma unroll
        for (int kc = 0; kc < 2; ++kc)
            #pragma unroll
            for (int m = 0; m < 4; ++m) {
                int base = (wr * 64 + m * 16 + colL) * 256;   // row&7 == c7
                union { int8v v; uint4 q[2]; } u8;
                u8.q[0] = *(const uint4*)&LB[buf][base + ((kc * 8 + ((quad * 2    ) ^ c7)) << 4)];
                u8.q[1] = *(const uint4*)&LB[buf][base + ((kc * 8 + ((quad * 2 + 1) ^ c7)) << 4)];
                af[kc][m] = u8.v;
            }
    };

    // full tile: 16 ds_read_b128 (B) + 32 mfma_scale per wave, no barriers
    auto computeTile = [&](int buf, f32x4 (&accf)[4][4]) {
        #pragma unroll
        for (int ks = 0; ks < 2; ++ks) {
            int8v bf[4];
            #pragma unroll
            for (int n = 0; n < 4; ++n) {
                int base = (wc * 64 + n * 16 + colL) * 256;   // row&7 == c7
                union { int8v v; uint4 q[2]; } u8;
                u8.q[0] = *(const uint4*)&LB[buf][base + ((ks * 8 + ((quad * 2    ) ^ c7)) << 4)];
                u8.q[1] = *(const uint4*)&LB[buf][base + ((ks * 8 + ((quad * 2 + 1) ^ c7)) << 4)];
                bf[n] = u8.v;
            }
            #pragma unroll
            for (int m = 0; m < 4; ++m)
                #pragma unroll
                for (int n = 0; n < 4; ++n)
                    accf[m][n] = __builtin_amdgcn_mfma_scale_f32_16x16x128_f8f6f4(
                        af[ks][m], bf[n], accf[m][n],
                        0 /*fmtA=fp8*/, 0 /*fmtB=fp8*/,
                        0, 0x7F7F7F7F,   // scale A = 1.0 (E8M0 127)
                        0, 0x7F7F7F7F);  // scale B = 1.0
        }
    };

    float total = 0.0f;

    // strip prologue: A -> LB[0], B(t0) -> LB[1]; one drain; A -> VGPRs.
    stageFull(0, bi);
    stageFull(1, bj);
    __syncthreads();                 // both panels landed
    readA(0);
    __syncthreads();                 // readA complete in ALL waves before LB[0] reuse
    int curB = 1;

    for (int t = t0; t < t1; ++t) {
        const bool more     = (t + 1 < t1);
        const bool crossing = (bj + 1 >= 64);          // block-uniform
        if (more)                                       // prefetch into free buf
            stageFull(1 - curB, crossing ? bi + 1 : bj + 1);

        f32x4 accf[4][4];
        #pragma unroll
        for (int m = 0; m < 4; ++m)
            #pragma unroll
            for (int n = 0; n < 4; ++n)
                accf[m][n] = f32x4{0.f, 0.f, 0.f, 0.f};

        computeTile(curB, accf);

        // epilogue: ||u||^2==1 -> term = exp2(fma(dot, LOG2E, -LOG2E))
        float local = 0.0f;
        if (bi != bj) {
            #pragma unroll
            for (int m = 0; m < 4; ++m)
                #pragma unroll
                for (int reg = 0; reg < 4; ++reg)
                    #pragma unroll
                    for (int n = 0; n < 4; ++n)
                        local += __builtin_amdgcn_exp2f(
                            fmaf(accf[m][n][reg], LOG2E, -LOG2E));
            local *= 2.0f;                             // mirrored block
        } else {
            #pragma unroll
            for (int m = 0; m < 4; ++m)
                #pragma unroll
                for (int reg = 0; reg < 4; ++reg) {
                    int i = wr * 64 + m * 16 + quad * 4 + reg;
                    #pragma unroll
                    for (int n = 0; n < 4; ++n) {
                        int j = wc * 64 + n * 16 + colL;
                        float e = __builtin_amdgcn_exp2f(
                            fmaf(accf[m][n][reg], LOG2E, -LOG2E));
                        local += (i == j) ? 0.0f : e;
                    }
                }
        }
        total += local;

        if (more) {
            __syncthreads();         // publish prefetched buf; curB reads done
            if (crossing) {          // pipeline restart at row boundary
                ++bi; bj = bi;
                readA(1 - curB);     // new A from the just-published buffer
                stageFull(curB, bj); // diag B into the freed buffer
                __syncthreads();     // drain readA + publish diag B (exposed)
                // curB unchanged: next tile computes from LB[curB]
            } else {
                ++bj;
                curB ^= 1;
            }
        }
    }

    // block-level reduction, once per kernel
    #pragma unroll
    for (int off = 32; off; off >>= 1) total += __shfl_down(total, off);
    if (lane == 0) red[wave] = total;
    __syncthreads();
    if (tid == 0)
        negp_part[bid] = red[0] + red[1] + red[2] + red[3];
}

// ---------------------------------------------------------------------------
// Kernel 3: finalize — reduce partials in double, emit scalar.
// ---------------------------------------------------------------------------
__global__ __launch_bounds__(256) void finalize_kernel(
    const float* __restrict__ spos_part, const float* __restrict__ negp_part,
    float* __restrict__ out) {

    int tid = threadIdx.x;
    double s = 0.0, ng = 0.0;
    for (int i = tid; i < 2048; i += 256) s  += (double)spos_part[i];
    for (int i = tid; i < GRID; i += 256) ng += (double)negp_part[i];

    #pragma unroll
    for (int off = 32; off; off >>= 1) {
        s  += __shfl_xor(s,  off);
        ng += __shfl_xor(ng, off);
    }
    __shared__ double sd[4], nd[4];
    int wave = tid >> 6, lane = tid & 63;
    if (lane == 0) { sd[wave] = s; nd[wave] = ng; }
    __syncthreads();
    if (tid == 0) {
        double st = sd[0] + sd[1] + sd[2] + sd[3];
        double nt = nd[0] + nd[1] + nd[2] + nd[3];
        double mean_star = nt / (8192.0 * 8191.0) + 1e-8;
        out[0] = (float)(-st / 8192.0 + 1.5 * mean_star);
    }
}

extern "C" void kernel_launch(void* const* d_in, const int* in_sizes, int n_in,
                              void* d_out, int out_size, void* d_ws, size_t ws_size,
                              hipStream_t stream) {
    const float* z1 = (const float*)d_in[0];
    const float* z2 = (const float*)d_in[1];
    float* out = (float*)d_out;

    char* ws = (char*)d_ws;
    unsigned char* z1n8  = (unsigned char*)ws;                         // 2 MB fp8
    float* spos_part     = (float*)(ws + (size_t)N_ROWS * DIM);        // 8 KB
    float* negp_part     = spos_part + 2048;                           // 2 KB

    norm_kernel<<<N_ROWS / 4, 256, 0, stream>>>(z1, z2, z1n8, spos_part);
    pair_kernel<<<GRID, 256, 0, stream>>>(z1n8, negp_part);
    finalize_kernel<<<1, 256, 0, stream>>>(spos_part, negp_part, out);
}

// Round 14
// 81.309 us; speedup vs baseline: 1.0302x; 1.0302x over previous
//
#include <hip/hip_runtime.h>
#include <hip/hip_bf16.h>

// FMICLLoss: out = -mean(s_pos) + ALPHA * ( sum_{i!=j} exp(-d2_ij/2) / (N(N-1)) + EPS )
// N=8192, D=256, SIGMA=1 (inv2s2=0.5), ALPHA=1.5, EPS=1e-8, NORM_EPS=1e-12.
//
// Round 14 = R12 (best measured: 82.8us) reverted, + two micro-tweaks:
//  - epilogue: 4 independent accumulators (breaks the 64-deep dependent
//    fp-add chain; reassociation err ~1e-7 vs 1.1e-2 threshold)
//  - the 32 five-tile strips go to bids 0..31 (earliest dispatched)
// R13's full-K 1-barrier variant measured +0.9us vs R12 -> staging drains
// were already hidden; pair's residual is MFMA floor (3.7us) + quarter-rate
// v_exp_f32 epilogue (~3us, structural: 67M exps) + static tail imbalance
// (~2us: 2080 = 512*4+32) + prologue/ramp. Harness-fixed: ~43.5us ws
// re-poison fill + ~3.5us restores + ~12us dispatch boundaries (atomic
// fusion failed R4/R10; coop launch failed R7).

#define N_ROWS 8192
#define DIM    256
#define LOG2E  1.4426950408889634f
#define GRID   512

typedef __attribute__((ext_vector_type(8))) int   int8v;
typedef __attribute__((ext_vector_type(4))) float f32x4;

#define GLDS16(gptr, lptr) \
  __builtin_amdgcn_global_load_lds((const __attribute__((address_space(1))) void*)(gptr), \
                                   (__attribute__((address_space(3))) void*)(lptr), 16, 0, 0)

// ---------------------------------------------------------------------------
// Kernel 1: row-normalize z1 -> fp8, s_pos via Gram trick (one reduce phase).
// ---------------------------------------------------------------------------
__global__ __launch_bounds__(256) void norm_kernel(
    const float* __restrict__ z1, const float* __restrict__ z2,
    unsigned char* __restrict__ z1n8, float* __restrict__ spos_part) {

    int tid  = threadIdx.x;
    int wave = tid >> 6, lane = tid & 63;
    int row  = blockIdx.x * 4 + wave;

    const float4 a = *(const float4*)(z1 + (size_t)row * DIM + lane * 4);
    const float4 b = *(const float4*)(z2 + (size_t)row * DIM + lane * 4);

    float s1  = a.x*a.x + a.y*a.y + a.z*a.z + a.w*a.w;
    float s2  = b.x*b.x + b.y*b.y + b.z*b.z + b.w*b.w;
    float s12 = a.x*b.x + a.y*b.y + a.z*b.z + a.w*b.w;
    #pragma unroll
    for (int off = 32; off; off >>= 1) {       // 3 interleaved chains (ILP)
        s1  += __shfl_xor(s1,  off);
        s2  += __shfl_xor(s2,  off);
        s12 += __shfl_xor(s12, off);
    }
    float r1 = __builtin_amdgcn_rsqf(s1);
    float r2 = __builtin_amdgcn_rsqf(s2);

    int lo = __builtin_amdgcn_cvt_pk_fp8_f32(a.x * r1, a.y * r1, 0,  false);
    int pk = __builtin_amdgcn_cvt_pk_fp8_f32(a.z * r1, a.w * r1, lo, true);
    ((int*)(z1n8 + (size_t)row * DIM))[lane] = pk;

    __shared__ float sp[4];
    if (lane == 0) {
        float c = s12 * r1 * r2;               // d_pos = 2 - 2c
        sp[wave] = logf(__expf(c - 1.0f) + 1e-8f) + 1.0f;
    }
    __syncthreads();
    if (tid == 0)
        spos_part[blockIdx.x] = sp[0] + sp[1] + sp[2] + sp[3];
}

// ---------------------------------------------------------------------------
// Kernel 2: A-stationary fused fp8 Z·Z^T + exp-sum, upper block-triangle.
// Row-major strips: bids 0..31 -> 5 tiles, bids 32..511 -> 4 tiles.
// A-frags in VGPRs per strip; B staged per tile (K=128 dbuf, 1-chunk-ahead).
// ---------------------------------------------------------------------------
__global__ __launch_bounds__(256, 2) void pair_kernel(
    const unsigned char* __restrict__ z1n8, float* __restrict__ negp_part) {

    __shared__ unsigned char LA[2][128 * 128];   // A panel (2 K-chunks), 32 KB
    __shared__ unsigned char LB[2][128 * 128];   // B double buffer, 32 KB
    __shared__ float red[4];

    const int tid = threadIdx.x, wave = tid >> 6, lane = tid & 63;
    const int bid = blockIdx.x;
    const int wr = wave >> 1, wc = wave & 1;
    const int quad = lane >> 4, colL = lane & 15;
    const int c7 = colL & 7;
    const int rl = lane >> 3, cl = lane & 7;

    // strip [t0, t1): 5-tile strips on the earliest-dispatched 32 blocks
    int t0, t1;
    if (bid < 32) { t0 = 5 * bid;              t1 = t0 + 5; }
    else          { t0 = 160 + 4 * (bid - 32); t1 = t0 + 4; }

    int bi = (int)((129.0f - sqrtf(16641.0f - 8.0f * (float)t0)) * 0.5f);
    if (bi < 0) bi = 0;
    while (64 * bi - (bi - 1) * bi / 2 > t0) --bi;
    while (64 * (bi + 1) - bi * (bi + 1) / 2 <= t0) ++bi;
    int bj = bi + (t0 - (64 * bi - (bi - 1) * bi / 2));

    // stage one 128x128B panel-chunk: per issue 64 lanes x 16B = 8 rows;
    // stored 16B-block cl receives logical block cl ^ rl (XOR swizzle) so
    // ds_read_b128 is conflict-free with no padding.
    auto stageP = [&](const unsigned char* gP, unsigned char* dst, int kc) {
        const size_t so = (size_t)(wave * 32 + rl) * DIM + kc * 128 + ((cl ^ rl) << 4);
        unsigned char* d = dst + (wave * 32) * 128;
        #pragma unroll
        for (int q = 0; q < 4; ++q)
            GLDS16(gP + so + q * 8 * DIM, d + q * 1024);
    };
    auto stageA = [&](int pbi) {
        const unsigned char* g = z1n8 + (size_t)pbi * (128 * DIM);
        stageP(g, LA[0], 0);
        stageP(g, LA[1], 1);
    };
    auto stageB = [&](int buf, int pbj, int kc) {
        stageP(z1n8 + (size_t)pbj * (128 * DIM), LB[buf], kc);
    };

    int8v af[2][4];                              // A-frags: 64 VGPRs, strip-resident
    auto readA = [&]() {
        #pragma unroll
        for (int kc = 0; kc < 2; ++kc)
            #pragma unroll
            for (int m = 0; m < 4; ++m) {
                int base = (wr * 64 + m * 16 + colL) * 128;
                union { int8v v; uint4 q[2]; } u8;
                u8.q[0] = *(const uint4*)&LA[kc][base + (((quad * 2    ) ^ c7) << 4)];
                u8.q[1] = *(const uint4*)&LA[kc][base + (((quad * 2 + 1) ^ c7) << 4)];
                af[kc][m] = u8.v;
            }
    };

    auto computeB = [&](int buf, int kc, f32x4 (&accf)[4][4]) {
        int8v bf[4];
        #pragma unroll
        for (int n = 0; n < 4; ++n) {
            int base = (wc * 64 + n * 16 + colL) * 128;
            union { int8v v; uint4 q[2]; } u8;
            u8.q[0] = *(const uint4*)&LB[buf][base + (((quad * 2    ) ^ c7) << 4)];
            u8.q[1] = *(const uint4*)&LB[buf][base + (((quad * 2 + 1) ^ c7) << 4)];
            bf[n] = u8.v;
        }
        #pragma unroll
        for (int m = 0; m < 4; ++m)
            #pragma unroll
            for (int n = 0; n < 4; ++n)
                accf[m][n] = __builtin_amdgcn_mfma_scale_f32_16x16x128_f8f6f4(
                    af[kc][m], bf[n], accf[m][n],
                    0 /*fmtA=fp8*/, 0 /*fmtB=fp8*/,
                    0, 0x7F7F7F7F,   // scale A = 1.0 (E8M0 127)
                    0, 0x7F7F7F7F);  // scale B = 1.0
    };

    float tot[4] = {0.f, 0.f, 0.f, 0.f};         // 4 chains: break add latency

    // strip prologue: A (both chunks) + first B chunk, one drain, A -> VGPRs
    stageA(bi);
    stageB(0, bj, 0);
    __syncthreads();
    readA();

    for (int t = t0; t < t1; ++t) {
        stageB(1, bj, 1);                        // prefetch c1 (window: compute c0)

        f32x4 accf[4][4];
        #pragma unroll
        for (int m = 0; m < 4; ++m)
            #pragma unroll
            for (int n = 0; n < 4; ++n)
                accf[m][n] = f32x4{0.f, 0.f, 0.f, 0.f};

        computeB(0, 0, accf);
        __syncthreads();                         // publish LB[1], free LB[0]

        const int  nbj      = bj + 1;
        const bool more     = (t + 1 < t1);
        const bool crossing = (nbj >= 64);       // block-uniform
        if (more && !crossing)
            stageB(0, nbj, 0);                   // prefetch next tile c0
                                                 // (window: compute c1 + epilogue)
        computeB(1, 1, accf);

        // epilogue: ||u||^2==1 -> term = exp2(fma(dot, LOG2E, -LOG2E));
        // 4 independent accumulators (indexed by n) break the dep chain.
        if (bi != bj) {
            float l[4] = {0.f, 0.f, 0.f, 0.f};
            #pragma unroll
            for (int m = 0; m < 4; ++m)
                #pragma unroll
                for (int reg = 0; reg < 4; ++reg)
                    #pragma unroll
                    for (int n = 0; n < 4; ++n)
                        l[n] += __builtin_amdgcn_exp2f(
                            fmaf(accf[m][n][reg], LOG2E, -LOG2E));
            #pragma unroll
            for (int n = 0; n < 4; ++n)
                tot[n] += 2.0f * l[n];           // mirrored block
        } else {
            float l[4] = {0.f, 0.f, 0.f, 0.f};
            #pragma unroll
            for (int m = 0; m < 4; ++m)
                #pragma unroll
                for (int reg = 0; reg < 4; ++reg) {
                    int i = wr * 64 + m * 16 + quad * 4 + reg;
                    #pragma unroll
                    for (int n = 0; n < 4; ++n) {
                        int j = wc * 64 + n * 16 + colL;
                        float e = __builtin_amdgcn_exp2f(
                            fmaf(accf[m][n][reg], LOG2E, -LOG2E));
                        l[n] += (i == j) ? 0.0f : e;
                    }
                }
            #pragma unroll
            for (int n = 0; n < 4; ++n) tot[n] += l[n];
        }

        if (more) {
            if (crossing) {                      // new row: reload A, restart pipe
                ++bi; bj = bi;
                stageA(bi);
                stageB(0, bj, 0);
                __syncthreads();                 // drain A + B0 (LB[1] reads done)
                readA();
            } else {
                bj = nbj;
                __syncthreads();                 // publish LB[0], free LB[1]
            }
        }
    }

    // block-level reduction, once per kernel
    float total = (tot[0] + tot[1]) + (tot[2] + tot[3]);
    #pragma unroll
    for (int off = 32; off; off >>= 1) total += __shfl_down(total, off);
    if (lane == 0) red[wave] = total;
    __syncthreads();
    if (tid == 0)
        negp_part[bid] = red[0] + red[1] + red[2] + red[3];
}

// ---------------------------------------------------------------------------
// Kernel 3: finalize — reduce partials in double, emit scalar.
// ---------------------------------------------------------------------------
__global__ __launch_bounds__(256) void finalize_kernel(
    const float* __restrict__ spos_part, const float* __restrict__ negp_part,
    float* __restrict__ out) {

    int tid = threadIdx.x;
    double s = 0.0, ng = 0.0;
    for (int i = tid; i < 2048; i += 256) s  += (double)spos_part[i];
    for (int i = tid; i < GRID; i += 256) ng += (double)negp_part[i];

    #pragma unroll
    for (int off = 32; off; off >>= 1) {
        s  += __shfl_xor(s,  off);
        ng += __shfl_xor(ng, off);
    }
    __shared__ double sd[4], nd[4];
    int wave = tid >> 6, lane = tid & 63;
    if (lane == 0) { sd[wave] = s; nd[wave] = ng; }
    __syncthreads();
    if (tid == 0) {
        double st = sd[0] + sd[1] + sd[2] + sd[3];
        double nt = nd[0] + nd[1] + nd[2] + nd[3];
        double mean_star = nt / (8192.0 * 8191.0) + 1e-8;
        out[0] = (float)(-st / 8192.0 + 1.5 * mean_star);
    }
}

extern "C" void kernel_launch(void* const* d_in, const int* in_sizes, int n_in,
                              void* d_out, int out_size, void* d_ws, size_t ws_size,
                              hipStream_t stream) {
    const float* z1 = (const float*)d_in[0];
    const float* z2 = (const float*)d_in[1];
    float* out = (float*)d_out;

    char* ws = (char*)d_ws;
    unsigned char* z1n8  = (unsigned char*)ws;                         // 2 MB fp8
    float* spos_part     = (float*)(ws + (size_t)N_ROWS * DIM);        // 8 KB
    float* negp_part     = spos_part + 2048;                           // 2 KB

    norm_kernel<<<N_ROWS / 4, 256, 0, stream>>>(z1, z2, z1n8, spos_part);
    pair_kernel<<<GRID, 256, 0, stream>>>(z1n8, negp_part);
    finalize_kernel<<<1, 256, 0, stream>>>(spos_part, negp_part, out);
}